// Round 1
// baseline (736.048 us; speedup 1.0000x reference)
//
#include <hip/hip_runtime.h>
#include <math.h>

#define N 320
#define NN (N * N)        // 102400
#define NV4 (N / 4)       // 80
#define KT 16

// ---------------- zero w buffer (102400 floats = 25600 float4) ----------------
__global__ __launch_bounds__(256) void zero_w_kernel(float* __restrict__ w) {
    int idx = blockIdx.x * 256 + threadIdx.x;
    ((float4*)w)[idx] = make_float4(0.f, 0.f, 0.f, 0.f);
}

// ---------------- colsum[e] = sum_t s[t][e] ----------------
__global__ __launch_bounds__(64) void colsum_kernel(const float* __restrict__ s,
                                                    float* __restrict__ colsum) {
    int e = blockIdx.x * 64 + threadIdx.x;
    float acc = 0.f;
    for (int t = 0; t < N; ++t) acc += s[t * N + e];
    colsum[e] = acc;
}

// ---------------- K1: G[iz][e][j] = sum_t s[t][e] * fut[i0+iz][t][j] ----------------
// 64x64 tile, 64 threads, 8x8 micro-tile. A=s^T and B=F_i are both naturally [t][*]
// in global memory -> no transpose needed on LDS staging.
__global__ __launch_bounds__(64, 4) void g_gemm_kernel(
    const float* __restrict__ s, const float* __restrict__ fut,
    float* __restrict__ G, int i0)
{
    const int iz = blockIdx.z;
    const int e0 = blockIdx.y * 64;
    const int j0 = blockIdx.x * 64;
    const int tid = threadIdx.x;
    const int tx = tid & 7;    // j micro: j = j0 + tx*8 + q
    const int ty = tid >> 3;   // e micro: e = e0 + ty*8 + p

    __shared__ float As[KT][64];   // [t][e]
    __shared__ float Bs[KT][64];   // [t][j]

    float acc[8][8];
#pragma unroll
    for (int p = 0; p < 8; ++p)
#pragma unroll
        for (int q = 0; q < 8; ++q) acc[p][q] = 0.f;

    const float4* s4 = (const float4*)s;
    const float4* f4 = (const float4*)(fut + (size_t)(i0 + iz) * NN);

    for (int k0 = 0; k0 < N; k0 += KT) {
#pragma unroll
        for (int v = 0; v < 4; ++v) {
            int idx = tid + 64 * v;
            int r = idx >> 4;      // 0..15 (t within tile)
            int c = idx & 15;      // float4 column
            float4 av = s4[(k0 + r) * NV4 + (e0 >> 2) + c];
            float4 bv = f4[(k0 + r) * NV4 + (j0 >> 2) + c];
            *(float4*)&As[r][c * 4] = av;
            *(float4*)&Bs[r][c * 4] = bv;
        }
        __syncthreads();
#pragma unroll
        for (int t = 0; t < KT; ++t) {
            float a[8], b[8];
            *(float4*)&a[0] = *(const float4*)&As[t][ty * 8];
            *(float4*)&a[4] = *(const float4*)&As[t][ty * 8 + 4];
            *(float4*)&b[0] = *(const float4*)&Bs[t][tx * 8];
            *(float4*)&b[4] = *(const float4*)&Bs[t][tx * 8 + 4];
#pragma unroll
            for (int p = 0; p < 8; ++p)
#pragma unroll
                for (int q = 0; q < 8; ++q) acc[p][q] += a[p] * b[q];
        }
        __syncthreads();
    }

    float* Gp = G + (size_t)iz * NN;
#pragma unroll
    for (int p = 0; p < 8; ++p) {
        int e = e0 + ty * 8 + p;
        *(float4*)&Gp[e * N + j0 + tx * 8]     = *(float4*)&acc[p][0];
        *(float4*)&Gp[e * N + j0 + tx * 8 + 4] = *(float4*)&acc[p][4];
    }
}

// ---------------- K2a: S[iz][e][j] = sum_k G[iz][e][k]*W[j][k] + colsum[e]*b[j] ------
// NT GEMM (both operands row-contiguous over k): transpose-on-LDS-store to [k][e],[k][j].
// Padding 68 keeps float4 reads 16B-aligned (68*4=272) and stores 2-way-max conflicts.
__global__ __launch_bounds__(64, 4) void score_gemm_kernel(
    const float* __restrict__ G, const float* __restrict__ W,
    const float* __restrict__ bvec, const float* __restrict__ colsum,
    float* __restrict__ S)
{
    const int iz = blockIdx.z;
    const int e0 = blockIdx.y * 64;
    const int j0 = blockIdx.x * 64;
    const int tid = threadIdx.x;
    const int tx = tid & 7;
    const int ty = tid >> 3;

    __shared__ float Ast[KT][68];   // [k][e]
    __shared__ float Bst[KT][68];   // [k][j]

    float acc[8][8];
#pragma unroll
    for (int p = 0; p < 8; ++p)
#pragma unroll
        for (int q = 0; q < 8; ++q) acc[p][q] = 0.f;

    const float4* G4 = (const float4*)(G + (size_t)iz * NN);
    const float4* W4 = (const float4*)W;

    for (int k0 = 0; k0 < N; k0 += KT) {
#pragma unroll
        for (int v = 0; v < 4; ++v) {
            int idx = tid + 64 * v;
            int ej = idx >> 2;     // 0..63
            int kq = idx & 3;      // float4 along k
            float4 gv = G4[(e0 + ej) * NV4 + (k0 >> 2) + kq];
            float4 wv = W4[(j0 + ej) * NV4 + (k0 >> 2) + kq];
            Ast[kq * 4 + 0][ej] = gv.x; Ast[kq * 4 + 1][ej] = gv.y;
            Ast[kq * 4 + 2][ej] = gv.z; Ast[kq * 4 + 3][ej] = gv.w;
            Bst[kq * 4 + 0][ej] = wv.x; Bst[kq * 4 + 1][ej] = wv.y;
            Bst[kq * 4 + 2][ej] = wv.z; Bst[kq * 4 + 3][ej] = wv.w;
        }
        __syncthreads();
#pragma unroll
        for (int t = 0; t < KT; ++t) {
            float a[8], b[8];
            *(float4*)&a[0] = *(const float4*)&Ast[t][ty * 8];
            *(float4*)&a[4] = *(const float4*)&Ast[t][ty * 8 + 4];
            *(float4*)&b[0] = *(const float4*)&Bst[t][tx * 8];
            *(float4*)&b[4] = *(const float4*)&Bst[t][tx * 8 + 4];
#pragma unroll
            for (int p = 0; p < 8; ++p)
#pragma unroll
                for (int q = 0; q < 8; ++q) acc[p][q] += a[p] * b[q];
        }
        __syncthreads();
    }

    float cs[8], bj[8];
#pragma unroll
    for (int p = 0; p < 8; ++p) cs[p] = colsum[e0 + ty * 8 + p];
    *(float4*)&bj[0] = *(const float4*)&bvec[j0 + tx * 8];
    *(float4*)&bj[4] = *(const float4*)&bvec[j0 + tx * 8 + 4];

    float* Sp = S + (size_t)iz * NN;
#pragma unroll
    for (int p = 0; p < 8; ++p) {
        int e = e0 + ty * 8 + p;
        float row[8];
#pragma unroll
        for (int q = 0; q < 8; ++q) row[q] = acc[p][q] + cs[p] * bj[q];
        *(float4*)&Sp[e * N + j0 + tx * 8]     = *(float4*)&row[0];
        *(float4*)&Sp[e * N + j0 + tx * 8 + 4] = *(float4*)&row[4];
    }
}

// ---------------- K2b: softmax rows of S over j, accumulate w[i][j] += sum_e ----------
// One wave per e-row (full 320 j in 5 regs/lane -> pure shuffle reductions, no LDS
// round-trip for softmax). Per-wave private LDS accumulator, one atomicAdd per j per block.
__global__ __launch_bounds__(256) void softmax_wsum_kernel(
    const float* __restrict__ S, float* __restrict__ w, int i0)
{
    const int iz = blockIdx.y;
    const int i  = i0 + iz;
    const int e0 = blockIdx.x * 32;
    const int tid  = threadIdx.x;
    const int lane = tid & 63;
    const int wv   = tid >> 6;

    __shared__ float wrow[4][320];
#pragma unroll
    for (int q = 0; q < 5; ++q) wrow[wv][lane + 64 * q] = 0.f;

    const float* Sp = S + ((size_t)iz * N + e0) * N;
    for (int pass = 0; pass < 8; ++pass) {
        const float* row = Sp + (size_t)(pass * 4 + wv) * N;
        float v[5];
#pragma unroll
        for (int q = 0; q < 5; ++q) v[q] = row[lane + 64 * q];
        float m = v[0];
#pragma unroll
        for (int q = 1; q < 5; ++q) m = fmaxf(m, v[q]);
        for (int off = 32; off; off >>= 1) m = fmaxf(m, __shfl_xor(m, off, 64));
        float sum = 0.f;
#pragma unroll
        for (int q = 0; q < 5; ++q) { v[q] = __expf(v[q] - m); sum += v[q]; }
        for (int off = 32; off; off >>= 1) sum += __shfl_xor(sum, off, 64);
        float inv = 1.0f / sum;
#pragma unroll
        for (int q = 0; q < 5; ++q) wrow[wv][lane + 64 * q] += v[q] * inv;
    }
    __syncthreads();
    {
        int j = tid;
        float t0 = wrow[0][j] + wrow[1][j] + wrow[2][j] + wrow[3][j];
        atomicAdd(&w[(size_t)i * N + j], t0);
    }
    if (tid < 64) {
        int j = 256 + tid;
        float t0 = wrow[0][j] + wrow[1][j] + wrow[2][j] + wrow[3][j];
        atomicAdd(&w[(size_t)i * N + j], t0);
    }
}

// ---------------- K3: out[i][k] = sum_j w[i][j] * s[j][k]  (65 MFLOP, trivial) --------
__global__ __launch_bounds__(64) void out_gemm_kernel(
    const float* __restrict__ w, const float* __restrict__ s,
    float* __restrict__ out)
{
    const int k = blockIdx.x * 64 + threadIdx.x;
    const int i = blockIdx.y;
    const float* wr = w + (size_t)i * N;
    float acc = 0.f;
    for (int j = 0; j < N; ++j) acc += wr[j] * s[j * N + k];
    out[(size_t)i * N + k] = acc;
}

extern "C" void kernel_launch(void* const* d_in, const int* in_sizes, int n_in,
                              void* d_out, int out_size, void* d_ws, size_t ws_size,
                              hipStream_t stream)
{
    const float* s    = (const float*)d_in[0];
    const float* fut  = (const float*)d_in[1];
    const float* W    = (const float*)d_in[2];
    const float* bvec = (const float*)d_in[3];
    float* out = (float*)d_out;

    // ws layout: [w: NN floats][colsum: N floats][pad][G: chunk*NN][S: chunk*NN]
    char* base = (char*)d_ws;
    float* wbuf   = (float*)base;
    float* colsum = wbuf + NN;
    size_t reserve = (((size_t)(NN + N)) * 4 + 255) & ~(size_t)255;
    float* scratch = (float*)(base + reserve);
    size_t avail = (ws_size > reserve) ? (ws_size - reserve) : 0;
    size_t per_i = (size_t)NN * 4 * 2;   // G slice + S slice
    int chunk = (int)(avail / per_i);
    if (chunk < 1) chunk = 1;
    if (chunk > N) chunk = N;

    zero_w_kernel<<<dim3(NN / 4 / 256), dim3(256), 0, stream>>>(wbuf);
    colsum_kernel<<<dim3(N / 64), dim3(64), 0, stream>>>(s, colsum);

    float* G = scratch;
    float* S = scratch + (size_t)chunk * NN;

    for (int i0 = 0; i0 < N; i0 += chunk) {
        int cn = (N - i0 < chunk) ? (N - i0) : chunk;
        g_gemm_kernel<<<dim3(5, 5, cn), dim3(64), 0, stream>>>(s, fut, G, i0);
        score_gemm_kernel<<<dim3(5, 5, cn), dim3(64), 0, stream>>>(G, W, bvec, colsum, S);
        softmax_wsum_kernel<<<dim3(10, cn), dim3(256), 0, stream>>>(S, wbuf, i0);
    }

    out_gemm_kernel<<<dim3(5, N), dim3(64), 0, stream>>>(wbuf, s, out);
}